// Round 1
// 196.322 us; speedup vs baseline: 1.0014x; 1.0014x over previous
//
#include <hip/hip_runtime.h>
#include <stdint.h>

#define N_BATCH 8
#define A_ 3
#define H_ 336
#define W_ 336
#define HW_ (H_*W_)        // 112896
#define M_ (A_*HW_)        // 338688
#define K_TOP 2000
#define POST_N 1000
#define NMS_THR_ 0.7f
#define NEG_ (-1e9f)
#define VALID_THR_ (-5e8f)
#define CAND_CAP 4096
#define NBINS 4096
#define BIN_SHIFT 20       // top 12 bits: sign+exp+3 mantissa
#define HBLK 32            // histogram/compact blocks per batch (256 blocks total)
#define SEG_ (M_/HBLK)     // 10584
#define XCLIP 4.135166556742356f  // log(1000/16)

#define NPAD 2048          // boxes padded to 32 chunks of 64
#define NW 32              // u64 words per adjacency row (ring UNPADDED: global_load_lds needs contiguity)
#define NCHUNK 32
#define RING 4             // ring slots (chunk c -> slot c&3)
#define RBLK 128           // candidate slots per k_rank block

typedef unsigned long long u64;

__device__ __forceinline__ unsigned int flip_key(float x) {
    unsigned int u = __float_as_uint(x);
    return (u & 0x80000000u) ? ~u : (u | 0x80000000u);
}
__device__ __forceinline__ float unflip_key(unsigned int k) {
    unsigned int u = (k & 0x80000000u) ? (k & 0x7fffffffu) : ~k;
    return __uint_as_float(u);
}

// Direct global->LDS DMA, 16 B/lane, no VGPR round-trip.
__device__ __forceinline__ void gload_lds16(const u64* g, u64* l) {
    __builtin_amdgcn_global_load_lds(
        (const __attribute__((address_space(1))) unsigned int*)(const void*)g,
        (__attribute__((address_space(3))) unsigned int*)(void*)l,
        16, 0, 0);
}

// ---------------- K1: quad LDS sub-histograms (wave parity) -> u16 sub-hist; zeroes cnt ----------------
__global__ __launch_bounds__(512) void k_hist(const float* __restrict__ logits,
                                              unsigned short* __restrict__ ghist,
                                              unsigned int* __restrict__ cnt) {
    __shared__ unsigned int h[4][NBINS];  // 64 KiB; 4-way parity split quarters same-bin atomic serialization
    int n = blockIdx.y, b = blockIdx.x;
    if (b == 0 && threadIdx.x < 2) cnt[n * 2 + threadIdx.x] = 0;  // replaces memset dispatch
    unsigned int* hf = &h[0][0];
    for (int i = threadIdx.x; i < 4 * NBINS; i += 512) hf[i] = 0;
    __syncthreads();
    int wp = (threadIdx.x >> 6) & 3;
    const float4* lp = (const float4*)(logits + (size_t)n * M_ + (size_t)b * SEG_);
    const int nq = SEG_ / 4;                 // 2646
    for (int q = threadIdx.x; q < nq; q += 512) {
        float4 v = lp[q];
        atomicAdd(&h[wp][flip_key(v.x) >> BIN_SHIFT], 1u);
        atomicAdd(&h[wp][flip_key(v.y) >> BIN_SHIFT], 1u);
        atomicAdd(&h[wp][flip_key(v.z) >> BIN_SHIFT], 1u);
        atomicAdd(&h[wp][flip_key(v.w) >> BIN_SHIFT], 1u);
    }
    __syncthreads();
    unsigned short* gp = ghist + ((size_t)n * HBLK + b) * NBINS;
    for (int i = threadIdx.x; i < NBINS; i += 512)
        gp[i] = (unsigned short)(h[0][i] + h[1][i] + h[2][i] + h[3][i]);
}

// ---------------- K2: fused threshold-scan + SEGMENTED compact ----------------
// hi segment (bin > B): cand[0..T), T < K_TOP guaranteed by B's definition.
// lo segment (bin == B): cand[CAND_CAP-1] growing downward. bin dominates key order,
// so every hi key > every lo key -> ranks decompose per segment (k_rank).
// Threshold prologue: thread t owns the 8 descending bins [8*(511-t), 8*(511-t)+8),
// sums them from uint4 loads into NAMED registers (no binsum LDS, no scratch),
// and the block scan is shfl-based (2 barriers instead of 18).
__global__ __launch_bounds__(512) void k_compact(const float* __restrict__ logits,
                                                 const unsigned short* __restrict__ ghist,
                                                 unsigned int* __restrict__ cnt,
                                                 u64* __restrict__ cand) {
    __shared__ unsigned int wsum[8];
    __shared__ u64 bufHi[2048];             // 16 KiB (block hi count <= T < 2000)
    __shared__ u64 bufLo[4096];             // 32 KiB
    __shared__ unsigned int lcntHi, lcntLo, gbaseHi, gbaseLo;
    __shared__ int Bsh;
    int n = blockIdx.y, b = blockIdx.x;
    int t = threadIdx.x;
    if (t == 0) { lcntHi = 0; lcntLo = 0; }
    // --- per-block threshold recompute (vectorized, register-resident) ---
    const unsigned short* base = ghist + (size_t)n * HBLK * NBINS;
    int tt = 511 - t;                        // thread t -> bins [8*tt, 8*tt+8), descending groups
    unsigned int c0 = 0, c1 = 0, c2 = 0, c3 = 0, c4 = 0, c5 = 0, c6 = 0, c7 = 0;
    #pragma unroll 8
    for (int sb = 0; sb < HBLK; ++sb) {
        uint4 v = *(const uint4*)(base + (size_t)sb * NBINS + 8 * tt);
        c0 += v.x & 0xffffu; c1 += v.x >> 16;
        c2 += v.y & 0xffffu; c3 += v.y >> 16;
        c4 += v.z & 0xffffu; c5 += v.z >> 16;
        c6 += v.w & 0xffffu; c7 += v.w >> 16;
    }
    unsigned int part = c0 + c1 + c2 + c3 + c4 + c5 + c6 + c7;
    // wave-level inclusive scan (no barriers), then cross-wave prefix (2 barriers)
    int wave = t >> 6, lane = t & 63;
    unsigned int sc = part;
    #pragma unroll
    for (int off = 1; off < 64; off <<= 1) {
        unsigned int v = __shfl_up(sc, off, 64);
        if (lane >= off) sc += v;
    }
    if (lane == 63) wsum[wave] = sc;
    __syncthreads();
    unsigned int wpre = 0;
    #pragma unroll
    for (int wv = 0; wv < 8; ++wv) wpre += (wv < wave) ? wsum[wv] : 0u;
    unsigned int incl = sc + wpre;
    unsigned int prefix = incl - part;
    if (prefix < K_TOP && incl >= K_TOP) {   // unique winner (part>0 required)
        unsigned int acc = prefix;
        int found = -1;
        // scan this thread's 8 bins from the HIGH bin (q=7) down, named regs only
        #define BSTEP(q, cq) if (found < 0) { if (acc + (cq) >= K_TOP) found = 8 * tt + (q); else acc += (cq); }
        BSTEP(7, c7) BSTEP(6, c6) BSTEP(5, c5) BSTEP(4, c4)
        BSTEP(3, c3) BSTEP(2, c2) BSTEP(1, c1) BSTEP(0, c0)
        #undef BSTEP
        Bsh = found;
    }
    __syncthreads();
    unsigned int B = (unsigned int)Bsh;
    // --- segmented compact pass ---
    const int qbase = b * SEG_;
    const float4* lp = (const float4*)(logits + (size_t)n * M_ + (size_t)qbase);
    const int nq = SEG_ / 4;
    for (int q = t; q < nq; q += 512) {
        float4 v = lp[q];
        float vv[4] = {v.x, v.y, v.z, v.w};
        #pragma unroll
        for (int e = 0; e < 4; ++e) {
            unsigned int u = flip_key(vv[e]);
            unsigned int bin = u >> BIN_SHIFT;
            if (bin >= B) {
                int qq = qbase + q * 4 + e;
                int a = qq / HW_;
                int hw = qq - a * HW_;
                unsigned int m = (unsigned int)(hw * A_ + a);  // score-order index
                u64 key = ((u64)u << 32) | (unsigned int)(~m);
                if (bin > B) {
                    unsigned int pos = atomicAdd(&lcntHi, 1u);
                    if (pos < 2048) bufHi[pos] = key;
                } else {
                    unsigned int pos = atomicAdd(&lcntLo, 1u);
                    if (pos < 4096) bufLo[pos] = key;
                }
            }
        }
    }
    __syncthreads();
    unsigned int Lhi = (lcntHi < 2048u) ? lcntHi : 2048u;
    unsigned int Llo = (lcntLo < 4096u) ? lcntLo : 4096u;
    if (t == 0) gbaseHi = atomicAdd(&cnt[n * 2], Lhi);
    if (t == 1) gbaseLo = atomicAdd(&cnt[n * 2 + 1], Llo);
    __syncthreads();
    u64* cp = cand + (size_t)n * CAND_CAP;
    for (unsigned int i = t; i < Lhi; i += 512)
        cp[gbaseHi + i] = bufHi[i];                 // global hi total = T < 2000 < CAND_CAP
    for (unsigned int i = t; i < Llo; i += 512) {
        unsigned int idx = CAND_CAP - 1u - (gbaseLo + i);
        if ((int)idx >= K_TOP) cp[idx] = bufLo[i];  // lo region never enters [0, K_TOP)
    }
}

// ---------------- K3: SEGMENTED rank-by-counting via SCALAR key stream + fused decode ----------------
// The key stream is wave-uniform -> route it through the scalar cache (s_load) and
// count with v_cmp_u64 on the VALU instead of serializing the per-CU LDS pipe.
// Thread layout: cl = t & 127 (candidate), tq = t >> 7 (stream quarter, wave-uniform).
// rank(hi_i) = #{j in hi: key_j > key_i}; rank(lo_i) = T + #{j in lo: key_j > key_i}.
__global__ __launch_bounds__(512) void k_rank(const u64* __restrict__ cand,
                                              const unsigned int* __restrict__ cnt,
                                              const float* __restrict__ anchors,
                                              const float* __restrict__ breg,
                                              float4* __restrict__ boxes,
                                              float* __restrict__ scores,
                                              float* __restrict__ areas) {
    __shared__ unsigned short psum[512];
    int n = blockIdx.y;
    int bx = blockIdx.x;
    unsigned int T = cnt[n * 2];                    // < 2000
    unsigned int Lc = cnt[n * 2 + 1];
    unsigned int Ls = (Lc < (unsigned int)(CAND_CAP - K_TOP)) ? Lc : (unsigned int)(CAND_CAP - K_TOP);
    int loStart = CAND_CAP - (int)Ls;
    int p0 = bx * RBLK;
    if (p0 >= (int)T && p0 + RBLK <= loStart) return;   // block fully inside the hole
    const u64* cp = cand + (size_t)n * CAND_CAP;
    int t = threadIdx.x;
    int cl = t & (RBLK - 1);                 // candidate-local index (0..127)
    int tq = t >> 7;                         // stream quarter 0..3 (uniform within a wave)
    int ci = p0 + cl;
    bool isHi = (ci < (int)T);
    bool isLo = (!isHi) && (ci >= loStart);
    u64 ki = (isHi || isLo) ? cp[ci] : 0ull;
    unsigned int r = 0;
    if (__any(isHi)) {                       // wave-uniform branch
        int len = (int)T;
        int qlen = (len + 3) >> 2;
        int j0 = tq * qlen;
        int j1 = j0 + qlen; if (j1 > len) j1 = len;
        j0 = __builtin_amdgcn_readfirstlane(j0);
        j1 = __builtin_amdgcn_readfirstlane(j1);
        unsigned int rh = 0;
        int j = j0;
        for (; j + 8 <= j1; j += 8) {        // 64 B of uniform keys -> merged s_loads
            u64 k0 = cp[j],     k1 = cp[j + 1], k2 = cp[j + 2], k3 = cp[j + 3];
            u64 k4 = cp[j + 4], k5 = cp[j + 5], k6 = cp[j + 6], k7 = cp[j + 7];
            rh += (k0 > ki) + (k1 > ki) + (k2 > ki) + (k3 > ki);
            rh += (k4 > ki) + (k5 > ki) + (k6 > ki) + (k7 > ki);
        }
        for (; j < j1; ++j) rh += (cp[j] > ki);
        if (isHi) r = rh;
    }
    if (__any(isLo)) {                       // wave-uniform branch
        int len = CAND_CAP - loStart;
        int qlen = (len + 3) >> 2;
        int j0 = loStart + tq * qlen;
        int j1 = j0 + qlen; if (j1 > CAND_CAP) j1 = CAND_CAP;
        j0 = __builtin_amdgcn_readfirstlane(j0);
        j1 = __builtin_amdgcn_readfirstlane(j1);
        unsigned int rl = 0;
        int j = j0;
        for (; j + 8 <= j1; j += 8) {
            u64 k0 = cp[j],     k1 = cp[j + 1], k2 = cp[j + 2], k3 = cp[j + 3];
            u64 k4 = cp[j + 4], k5 = cp[j + 5], k6 = cp[j + 6], k7 = cp[j + 7];
            rl += (k0 > ki) + (k1 > ki) + (k2 > ki) + (k3 > ki);
            rl += (k4 > ki) + (k5 > ki) + (k6 > ki) + (k7 > ki);
        }
        for (; j < j1; ++j) rl += (cp[j] > ki);
        if (isLo) r = rl;
    }
    psum[t] = (unsigned short)r;
    __syncthreads();
    if (t < RBLK && (isHi || isLo)) {        // tq==0 threads: own ki/isHi/isLo are valid
        unsigned int rank = (isLo ? T : 0u)
                          + psum[t] + psum[t + 128] + psum[t + 256] + psum[t + 384];
        if (rank < K_TOP) {
            unsigned int u = (unsigned int)(ki >> 32);
            unsigned int m = ~((unsigned int)ki);
            float logit = unflip_key(u);
            int a = (int)(m % 3u);
            int hw = (int)(m / 3u);
            float4 anc = ((const float4*)anchors)[(size_t)n * M_ + m];
            size_t rb = ((size_t)n * 12 + a * 4) * HW_ + hw;
            float dx = breg[rb];
            float dy = breg[rb + (size_t)HW_];
            float dw = breg[rb + (size_t)2 * HW_];
            float dh = breg[rb + (size_t)3 * HW_];
            float score = 1.0f / (1.0f + expf(-logit));
            float w = anc.z - anc.x + 1.0f;
            float h = anc.w - anc.y + 1.0f;
            float cx = anc.x + 0.5f * w;
            float cy = anc.y + 0.5f * h;
            dw = fminf(dw, XCLIP);
            dh = fminf(dh, XCLIP);
            float pcx = dx * w + cx;
            float pcy = dy * h + cy;
            float pw = expf(dw) * w;
            float ph = expf(dh) * h;
            float x1 = pcx - 0.5f * pw;
            float y1 = pcy - 0.5f * ph;
            float x2 = pcx + 0.5f * pw - 1.0f;
            float y2 = pcy + 0.5f * ph - 1.0f;
            x1 = fminf(fmaxf(x1, 0.0f), 1332.0f);
            y1 = fminf(fmaxf(y1, 0.0f), 799.0f);
            x2 = fminf(fmaxf(x2, 0.0f), 1332.0f);
            y2 = fminf(fmaxf(y2, 0.0f), 799.0f);
            float ww = x2 - x1 + 1.0f;
            float hh = y2 - y1 + 1.0f;
            bool keep = (ww >= 0.0f) && (hh >= 0.0f);  // MIN_SIZE = 0
            int g = n * K_TOP + (int)rank;
            boxes[g] = make_float4(x1, y1, x2, y2);
            scores[g] = keep ? score : NEG_;
            areas[g] = ww * hh;
        }
    }
}

// ---------------- K5: adjacency bitmask, UPPER-TRIANGLE tiles only ----------------
#define JT 512   // j's per block tile (8 u64 words)
#define RT 64    // rows per block tile (1 chunk)
__global__ __launch_bounds__(256) void k_edges(const float4* __restrict__ boxes,
                                               const float* __restrict__ areas,
                                               u64* __restrict__ adj) {
    int n = blockIdx.z;
    int by = blockIdx.y;                   // row chunk 0..31
    int bx = blockIdx.x;                   // word tile 0..3 (words bx*8..bx*8+7)
    if (by > bx * 8 + 7) return;           // all words below diagonal: never consumed
    __shared__ float4 jb[JT];
    __shared__ float ja[JT];
    int r0 = by * RT;
    int j0 = bx * JT;
    for (int j = threadIdx.x; j < JT; j += 256) {
        int jj = j0 + j;
        if (jj < K_TOP) {
            jb[j] = boxes[(size_t)n * K_TOP + jj];
            ja[j] = areas[(size_t)n * K_TOP + jj];
        } else {
            jb[j] = make_float4(-1e8f, -1e8f, -1e8f, -1e8f);  // IoU vs anything = 0
            ja[j] = 0.0f;
        }
    }
    __syncthreads();
    int i = r0 + (threadIdx.x >> 2);       // 4 threads per row
    if (i >= K_TOP) return;
    float4 bi = boxes[(size_t)n * K_TOP + i];
    float ai = areas[(size_t)n * K_TOP + i];
    #pragma unroll
    for (int rep = 0; rep < 2; ++rep) {
        int wl = (threadIdx.x & 3) + rep * 4;  // word-in-tile 0..7
        u64 bits = 0;
        int base = wl * 64;
        #pragma unroll 8
        for (int b = 0; b < 64; ++b) {
            float4 bj = jb[base + b];
            float xx1 = fmaxf(bi.x, bj.x);
            float yy1 = fmaxf(bi.y, bj.y);
            float xx2 = fminf(bi.z, bj.z);
            float yy2 = fminf(bi.w, bj.w);
            float inter = fmaxf(xx2 - xx1 + 1.0f, 0.0f) * fmaxf(yy2 - yy1 + 1.0f, 0.0f);
            float iou = inter / (ai + ja[base + b] - inter);
            bits |= ((u64)(iou > NMS_THR_)) << b;
        }
        adj[((size_t)n * NPAD + i) * NW + (j0 >> 6) + wl] = bits;
    }
}

// ---------------- K6: wave-specialized greedy NMS (ballot-Jacobi + early exit + 8-wide sup-OR) ----------------
__global__ __launch_bounds__(256) void k_resolve(const float4* __restrict__ boxes,
                                                 const float* __restrict__ scores,
                                                 const u64* __restrict__ adj,
                                                 float* __restrict__ out) {
    __shared__ u64 ring[RING][64 * NW];     // 4 x 16 KiB = 64 KiB, CONTIGUOUS (DMA layout)
    __shared__ float sls[NPAD];             // 8 KiB
    __shared__ unsigned char alive[NPAD];   // 2 KiB (indices >= K_TOP stay 0)
    __shared__ int ready[RING];             // slot s holds chunk c when ready[s]==c+1
    __shared__ int progress;                // # chunks fully resolved
    __shared__ unsigned int scanbuf[256];
    int n = blockIdx.x;
    int tid = threadIdx.x;
    int wave = tid >> 6, lane = tid & 63;
    const u64* ab = adj + (size_t)n * NPAD * NW;

    for (int i = tid; i < NPAD; i += 256) {
        sls[i] = (i < K_TOP) ? scores[(size_t)n * K_TOP + i] : NEG_;
        alive[i] = 0;
    }
    if (tid < RING) ready[tid] = 0;
    if (tid == 0) progress = 0;
    __syncthreads();  // init visible to all waves (the ONLY barrier before the epilogue)

    if (wave == 0) {
        // ---- resolver ----
        u64 supreg = 0;  // lane w (w<32) holds suppressed-mask word w
        int survTot = 0;
        for (int c = 0; c < NCHUNK; ++c) {
            int slot = c & (RING - 1);
            while (__hip_atomic_load(&ready[slot], __ATOMIC_ACQUIRE,
                                     __HIP_MEMORY_SCOPE_WORKGROUP) != c + 1)
                __builtin_amdgcn_s_sleep(1);
            int k = lane;
            int gi = c * 64 + k;
            // symmetric adjacency: row gi word c == column k of the diag block
            u64 colk = ring[slot][k * NW + c];
            u64 supc = __shfl(supreg, c, 64);
            bool validk = (sls[gi] > VALID_THR_) && !((supc >> k) & 1ull);
            u64 below = (k == 0) ? 0ull : ((1ull << k) - 1ull);
            u64 rel = colk & below;
            // ballot-Jacobi: well-founded in k -> unique fixed point == greedy result
            bool a = validk;
            u64 am = __ballot(a);
            while (true) {
                bool anew = validk && ((am & rel) == 0ull);
                u64 am2 = __ballot(anew);
                if (am2 == am) { a = anew; break; }
                am = am2;
            }
            alive[gi] = a ? 1 : 0;
            int nal = (int)__popcll(am);
            survTot += nal;
            if (survTot >= POST_N) {
                // later boxes can't affect the first POST_N output rows -> done.
                if (lane == 0)
                    __hip_atomic_store(&progress, NCHUNK, __ATOMIC_RELEASE,
                                       __HIP_MEMORY_SCOPE_WORKGROUP);
                break;
            }
            // sup-OR: set bits of am (register-uniform), parity-split across wave halves,
            // 8 independent ds_reads per group before one waitcnt (idempotent dup pads).
            int w = lane & 31, half = lane >> 5;
            u64 acc = 0;
            u64 m = am & (half ? 0xAAAAAAAAAAAAAAAAull : 0x5555555555555555ull);
            while (m) {
                int kk[8];
                kk[0] = __ffsll((unsigned long long)m) - 1; m &= m - 1;
                #pragma unroll
                for (int e = 1; e < 8; ++e) {
                    kk[e] = m ? (__ffsll((unsigned long long)m) - 1) : kk[0];
                    if (m) m &= m - 1;
                }
                u64 r0 = ring[slot][kk[0] * NW + w];
                u64 r1 = ring[slot][kk[1] * NW + w];
                u64 r2 = ring[slot][kk[2] * NW + w];
                u64 r3 = ring[slot][kk[3] * NW + w];
                u64 r4 = ring[slot][kk[4] * NW + w];
                u64 r5 = ring[slot][kk[5] * NW + w];
                u64 r6 = ring[slot][kk[6] * NW + w];
                u64 r7 = ring[slot][kk[7] * NW + w];
                acc |= (r0 | r1) | (r2 | r3) | ((r4 | r5) | (r6 | r7));
            }
            acc |= __shfl_down(acc, 32);    // fold half 1 into half 0
            if (lane < 32) supreg |= acc;
            if (lane == 0)
                __hip_atomic_store(&progress, c + 1, __ATOMIC_RELEASE,
                                   __HIP_MEMORY_SCOPE_WORKGROUP);
        }
    } else {
        // ---- prefetchers: wave v handles chunks v-1, v+2, v+5, ... ----
        for (int c = wave - 1; c < NCHUNK; c += 3) {
            int slot = c & (RING - 1);
            int p;
            while ((p = __hip_atomic_load(&progress, __ATOMIC_ACQUIRE,
                                          __HIP_MEMORY_SCOPE_WORKGROUP)) < c - 3)
                __builtin_amdgcn_s_sleep(1);
            if (p >= NCHUNK) break;          // resolver done: skip useless DMA tail
            const u64* src = ab + (size_t)c * 64 * NW + lane * 2;  // 16 B per lane
            u64* dst = &ring[slot][0];
            #pragma unroll
            for (int it = 0; it < 16; ++it)   // 16 x 1 KiB DMA, back-to-back
                gload_lds16(src + (size_t)it * 128, dst + it * 128);
            __builtin_amdgcn_s_waitcnt(0);    // drain this wave's DMA before publishing
            if (lane == 0)
                __hip_atomic_store(&ready[slot], c + 1, __ATOMIC_RELEASE,
                                   __HIP_MEMORY_SCOPE_WORKGROUP);
        }
    }
    __syncthreads();

    // --- order-preserving compaction of survivors -> output rows ---
    // i0 covers [0,2048): all arrays are NPAD-sized and alive[>=K_TOP]==0 (R3 lesson).
    int i0 = tid * 8;
    unsigned int c2 = 0;
    for (int i = i0; i < i0 + 8; ++i) c2 += alive[i];
    scanbuf[tid] = c2;
    __syncthreads();
    for (int off = 1; off < 256; off <<= 1) {
        unsigned int v = scanbuf[tid];
        unsigned int addv = (tid >= off) ? scanbuf[tid - off] : 0u;
        __syncthreads();
        scanbuf[tid] = v + addv;
        __syncthreads();
    }
    unsigned int r = scanbuf[tid] - c2;
    unsigned int total = scanbuf[255];
    float* op = out + (size_t)n * POST_N * 5;
    const float4* bb = boxes + (size_t)n * K_TOP;
    for (int i = i0; i < i0 + 8; ++i) {
        if (alive[i]) {
            if (r < POST_N) {
                float4 b = bb[i];
                op[r * 5 + 0] = b.x;
                op[r * 5 + 1] = b.y;
                op[r * 5 + 2] = b.z;
                op[r * 5 + 3] = b.w;
                op[r * 5 + 4] = sls[i];
            }
            r++;
        }
    }
    unsigned int S = (total > POST_N) ? POST_N : total;
    for (unsigned int q = S + tid; q < POST_N; q += 256) {
        op[q * 5 + 0] = 0.0f;
        op[q * 5 + 1] = 0.0f;
        op[q * 5 + 2] = 0.0f;
        op[q * 5 + 3] = 0.0f;
        op[q * 5 + 4] = 0.0f;
    }
}

extern "C" void kernel_launch(void* const* d_in, const int* in_sizes, int n_in,
                              void* d_out, int out_size, void* d_ws, size_t ws_size,
                              hipStream_t stream) {
    const float* anchors = (const float*)d_in[0];
    const float* logits  = (const float*)d_in[1];
    const float* breg    = (const float*)d_in[2];
    float* out = (float*)d_out;
    char* ws = (char*)d_ws;

    // ws layout (bytes) — adj ALIASES ghist+cand (both dead before k_edges writes adj):
    // [0, 64)               cnt    : u32[8][2]           (zeroed by k_hist block 0: hi/lo counters)
    // [128, 2097280)        ghist  : u16[8][HBLK=32][4096]   \ dead after k_compact / k_rank
    // [2097280, 2359424)    cand   : u64[8][4096]            /   (hi seg up, lo seg down)
    // [128, 4194432)        adj    : u64[8][2048][32]    (written by k_edges after k_rank;
    //                                                     below-diagonal words stay poison, never read)
    // [4194432, 4450432)    boxes  : float4[8][2000]
    // [4450432, 4514432)    scores : f32[8][2000]
    // [4514432, 4578432)    areas  : f32[8][2000]
    unsigned int* cnt     = (unsigned int*)(ws);
    unsigned short* ghist = (unsigned short*)(ws + 128);
    u64* cand             = (u64*)(ws + 2097280);
    u64* adj              = (u64*)(ws + 128);
    float4* boxes         = (float4*)(ws + 4194432);
    float* scores         = (float*)(ws + 4450432);
    float* areas          = (float*)(ws + 4514432);

    k_hist<<<dim3(HBLK, 8), 512, 0, stream>>>(logits, ghist, cnt);
    k_compact<<<dim3(HBLK, 8), 512, 0, stream>>>(logits, ghist, cnt, cand);
    k_rank<<<dim3(CAND_CAP / RBLK, 8), 512, 0, stream>>>(cand, cnt, anchors, breg,
                                                         boxes, scores, areas);
    k_edges<<<dim3(NPAD / JT, NPAD / RT, 8), 256, 0, stream>>>(boxes, areas, adj);
    k_resolve<<<8, 256, 0, stream>>>(boxes, scores, adj, out);
}